// Round 10
// baseline (220.828 us; speedup 1.0000x reference)
//
#include <hip/hip_runtime.h>
#include <hip/hip_bf16.h>
#include <math.h>

#define S_LEN 2048
#define HID   1024
#define NHEAD 16

using bf16x8 = __attribute__((ext_vector_type(8))) short;
using bf16x4 = __attribute__((ext_vector_type(4))) short;
using f32x4  = __attribute__((ext_vector_type(4))) float;

__device__ __forceinline__ float bf2f(short s) {
  union { unsigned u; float f; } c;
  c.u = ((unsigned)(unsigned short)s) << 16;
  return c.f;
}
__device__ __forceinline__ short f2bf(float f) {
  union { float f; unsigned u; } c; c.f = f;
  unsigned u = c.u;
  unsigned r = (u + 0x7fffu + ((u >> 16) & 1u)) >> 16;
  return (short)r;
}
__device__ __forceinline__ float loadf(const void* base, long idx, int is_bf) {
  return is_bf ? bf2f(((const short*)base)[idx]) : ((const float*)base)[idx];
}
__device__ __forceinline__ void gl_lds16(const void* g, void* l) {
  __builtin_amdgcn_global_load_lds(
      (const __attribute__((address_space(1))) void*)g,
      (__attribute__((address_space(3))) void*)l, 16, 0, 0);
}

// Convert x + 4 weights to bf16 (or copy). blockIdx.y: 0=x (2M), 1..4=W (1M each).
// Detection folded in; block (0,0) publishes flags[0..1].
__global__ __launch_bounds__(256) void convert5(
    const void* __restrict__ s0, const void* __restrict__ s1, const void* __restrict__ s2,
    const void* __restrict__ s3, const void* __restrict__ s4,
    short* __restrict__ d0, short* __restrict__ d1, short* __restrict__ d2,
    short* __restrict__ d3, short* __restrict__ d4,
    const int* __restrict__ modw, int* __restrict__ flags) {
  __shared__ int sh_isbf;
  const int t = threadIdx.x;

  if (t < 64) {
    const unsigned* xw = (const unsigned*)s0;
    int cnt = 0;
    for (int i = t; i < 1024; i += 64) {
      const unsigned fld = (xw[i] >> 7) & 0xFFu;
      cnt += (fld >= 100u && fld <= 135u) ? 1 : 0;
    }
    for (int m = 1; m < 64; m <<= 1) cnt += __shfl_xor(cnt, m);
    if (t == 0) sh_isbf = (cnt >= 512) ? 1 : 0;
  }
  __syncthreads();
  const int is_bf = sh_isbf;

  if (blockIdx.x == 0 && blockIdx.y == 0 && t < 64) {
    int odd = 0;
    for (int i = 0; i < 4; ++i) {
      const int wv = modw[2 * (t + 64 * i) + 1];
      odd += (wv != 0) ? 1 : 0;
    }
    for (int m = 1; m < 64; m <<= 1) odd += __shfl_xor(odd, m);
    if (t == 0) {
      flags[0] = is_bf;
      flags[1] = (odd == 0) ? 1 : 0;
    }
  }

  const int a = blockIdx.y;
  const void* src = (a == 0) ? s0 : (a == 1) ? s1 : (a == 2) ? s2 : (a == 3) ? s3 : s4;
  short* dst = (a == 0) ? d0 : (a == 1) ? d1 : (a == 2) ? d2 : (a == 3) ? d3 : d4;
  const long n = (a == 0) ? (2L << 20) : (1L << 20);
  long i = (long)(blockIdx.x * 256 + t) * 8;
  const long stride = (long)gridDim.x * 256 * 8;
  if (is_bf) {
    for (; i < n; i += stride)
      *(bf16x8*)(dst + i) = *(const bf16x8*)((const short*)src + i);
  } else {
    for (; i < n; i += stride) {
      const float* p = (const float*)src + i;
      bf16x8 r;
#pragma unroll
      for (int j = 0; j < 8; ++j) r[j] = f2bf(p[j]);
      *(bf16x8*)(dst + i) = r;
    }
  }
}

// Pure-bf16 B^T GEMM, BM x BN tile, BK=64 staged as TWO 32-wide panels
// [buf][panel][row][32] (R9 measured-best). 2-phase double-buffered;
// ONE __syncthreads per 64-k step. C[m,n] = A[m,:].W[n,:] + bias[n]; fp32 acc.
// <128,64>: 4 waves 2m x 2n, MI=4 NI=2 (QKV). <64,64>: 1m x 4n, MI=4 NI=1.
template <int BM, int BN>
__global__ __launch_bounds__(256) void gemm_bt3(
    const short* __restrict__ A,
    const short* __restrict__ W0, const short* __restrict__ W1, const short* __restrict__ W2,
    const void* __restrict__ b0, const void* __restrict__ b1, const void* __restrict__ b2,
    void* __restrict__ C0, void* __restrict__ C1, void* __restrict__ C2,
    const int* __restrict__ flags, int nbn, int store_f32)
{
  constexpr int K = 1024;
  constexpr int N = 1024;
  constexpr int NKT = K / 64;               // 16 k-steps
  constexpr int WM = (BM == 128) ? 2 : 1;
  constexpr int WN = 4 / WM;
  constexpr int MI = (BM / 16) / WM;
  constexpr int NI = (BN / 16) / WN;
  constexpr int RPA = BM / 16;              // 1KB regions per A panel
  constexpr int RPB = BN / 16;
  __shared__ short As[2][2][BM * 32];
  __shared__ short Bs[2][2][BN * 32];

  const int t = threadIdx.x;
  const int w = t >> 6, lane = t & 63;
  const int l15 = lane & 15, quad = lane >> 4;
  const int wm = w / WN, wn = w % WN;
  const int is_bf = flags[0];

  const int mat = blockIdx.x / nbn;
  const int n0 = (blockIdx.x % nbn) * BN;
  const int m0 = blockIdx.y * BM;

  const short* W  = (mat == 0) ? W0 : (mat == 1 ? W1 : W2);
  const void* bia = (mat == 0) ? b0 : (mat == 1 ? b1 : b2);
  void*       C   = (mat == 0) ? C0 : (mat == 1 ? C1 : C2);

  f32x4 acc[MI][NI];
  for (int mi = 0; mi < MI; ++mi)
    for (int ni = 0; ni < NI; ++ni)
      for (int r = 0; r < 4; ++r) acc[mi][ni][r] = 0.f;

  // staging lane map: 16 rows x 64B per 1KB region
  const int srow = lane >> 2;               // 0..15
  const int sch  = (lane & 3) * 8;          // 0,8,16,24 shorts

  auto stage = [&](int kt, int buf) {
    for (int g = w; g < 2 * RPA; g += 4) {  // A regions: panel p, rows r0..r0+15
      const int p = g / RPA, r0 = (g % RPA) * 16;
      gl_lds16(A + (long)(m0 + r0 + srow) * K + kt * 64 + p * 32 + sch,
               &As[buf][p][r0 * 32]);
    }
    for (int g = w; g < 2 * RPB; g += 4) {
      const int p = g / RPB, r0 = (g % RPB) * 16;
      gl_lds16(W + (long)(n0 + r0 + srow) * K + kt * 64 + p * 32 + sch,
               &Bs[buf][p][r0 * 32]);
    }
  };

  stage(0, 0);
  int cur = 0;
  for (int kt = 0; kt < NKT; ++kt) {
    __syncthreads();                        // step kt landed; prev reads done
    if (kt + 1 < NKT) stage(kt + 1, cur ^ 1);  // next step flies under MFMA

    bf16x8 af[MI][2], bfr[NI][2];
    for (int p = 0; p < 2; ++p) {
      for (int mi = 0; mi < MI; ++mi)
        af[mi][p] = *(const bf16x8*)&As[cur][p][(wm * (MI * 16) + mi * 16 + l15) * 32 + quad * 8];
      for (int ni = 0; ni < NI; ++ni)
        bfr[ni][p] = *(const bf16x8*)&Bs[cur][p][(wn * (NI * 16) + ni * 16 + l15) * 32 + quad * 8];
    }
    for (int p = 0; p < 2; ++p)
      for (int mi = 0; mi < MI; ++mi)
        for (int ni = 0; ni < NI; ++ni)
          acc[mi][ni] = __builtin_amdgcn_mfma_f32_16x16x32_bf16(af[mi][p], bfr[ni][p], acc[mi][ni], 0, 0, 0);
    cur ^= 1;
  }

  for (int ni = 0; ni < NI; ++ni) {
    const int col = n0 + wn * (NI * 16) + ni * 16 + l15;
    const float bv = loadf(bia, col, is_bf);
    for (int mi = 0; mi < MI; ++mi) {
      const int row = m0 + wm * (MI * 16) + mi * 16 + quad * 4;
      for (int r = 0; r < 4; ++r) {
        const float v = acc[mi][ni][r] + bv;
        const long idx = (long)(row + r) * N + col;
        if (store_f32) ((float*)C)[idx] = v;
        else           ((short*)C)[idx] = f2bf(v);
      }
    }
  }
}

// ============================================================================
// Flash attention, LDS-traffic-reduced: K fragments read DIRECTLY from global
// (L2-resident) per wave -- no K LDS staging, no K LDS reads. Only V (transposed)
// and the P strip live in LDS. V double-buffered, ONE barrier per tile
// (write-before-barrier; safe: waves pass bar(kt+4) only after kt's PV).
// Strides 88 shorts (176B, b128-aligned): P writes 8-way -> 2-way banked,
// PV reads 4-way -> 2-way. 8-wave blocks, 16 q-rows/wave, 4-way split-K,
// strip pairs (p,15-p). MAX-FREE softmax. K-frag loads issue at iteration top;
// their L2 latency hides under V-write + barrier.
// ============================================================================
#define POSTRIDE (2L * 1024 * 1024)
__global__ __launch_bounds__(512, 4) void attn_split(
    const short* __restrict__ Q, const short* __restrict__ Kg, const short* __restrict__ Vg,
    const int* __restrict__ mod, const void* __restrict__ cmw,
    const int* __restrict__ flags,
    short* __restrict__ PO, float* __restrict__ PL)
{
  __shared__ short Vt[2][64 * 88];
  __shared__ short Ps[8 * 16 * 88];
  __shared__ float cm[9];
  __shared__ int mods[2048];

  const int t = threadIdx.x;            // 0..511
  const int w = t >> 6, lane = t & 63;  // 8 waves
  const int l15 = lane & 15, quad = lane >> 4;
  const int h = blockIdx.y;
  const int p   = blockIdx.x >> 2;      // 0..7 -> strips {p, 15-p}
  const int par = blockIdx.x & 3;       // k-parity 0..3
  const int m64 = flags[1];
  const float KL2E = 0.125f * 1.44269504089f;   // 0.125 * log2(e)

  if (t < 9) cm[t] = loadf(cmw, t, flags[0]) * 1.44269504089f;
  for (int i = t; i < 2048; i += 512) mods[i] = mod[i << m64];
  __syncthreads();

  short* POp = PO + (long)par * POSTRIDE;
  const int vkp = t & 63, vdc = (t >> 6) * 8;   // V staging: 64 k x 8 d-groups

  for (int si = 0; si < 2; ++si) {
    const int strip = si ? 15 - p : p;
    const int q0 = strip * 128;
    const int ktmax = 2 * strip + 1;
    const int qw0 = q0 + w * 16;        // this wave's first q-row

    const short* qb = Q + (long)(qw0 + l15) * HID + h * 64 + quad * 8;
    const bf16x8 aq0 = *(const bf16x8*)qb;
    const bf16x8 aq1 = *(const bf16x8*)(qb + 32);

    int mrow[4];
    for (int r = 0; r < 4; ++r) mrow[r] = mods[qw0 + quad * 4 + r];

    float lsum[4];
    f32x4 acc_o[4];
    for (int r = 0; r < 4; ++r) lsum[r] = 0.f;
    for (int ni = 0; ni < 4; ++ni)
      for (int r = 0; r < 4; ++r) acc_o[ni][r] = 0.f;

    if (par <= ktmax) {
      // V preload for first tile of this parity
      bf16x8 rv = *(const bf16x8*)(Vg + (long)(par * 64) * HID + h * 64 +
                                   (long)vkp * HID + vdc);
      int cur = 0;
      // barrier before first V write of this strip: prior strip's PV readers
      // of Vt[cur] must be done (strips reuse buffers)
      __syncthreads();
      for (int kt = par; kt <= ktmax; kt += 4) {
        const bool act = (kt * 64 <= qw0 + 15);  // wave-uniform

        // K fragments for this tile: straight from global (L2-hot).
        bf16x8 kc0[4], kc1[4];
        if (act) {
          const short* kgb = Kg + (long)(kt * 64) * HID + h * 64;
#pragma unroll
          for (int nt = 0; nt < 4; ++nt) {
            kc0[nt] = *(const bf16x8*)(kgb + (long)(nt * 16 + l15) * HID + quad * 8);
            kc1[nt] = *(const bf16x8*)(kgb + (long)(nt * 16 + l15) * HID + 32 + quad * 8);
          }
        }

        // stage V tile kt into Vt[cur] (transpose via scalar writes)
#pragma unroll
        for (int j = 0; j < 8; ++j) Vt[cur][(vdc + j) * 88 + vkp] = rv[j];
        __syncthreads();               // Vt[cur] visible to all waves
        if (kt + 4 <= ktmax)           // next V flies under compute
          rv = *(const bf16x8*)(Vg + (long)((kt + 4) * 64) * HID + h * 64 +
                                (long)vkp * HID + vdc);

        if (act) {
          f32x4 sc[4];
          __builtin_amdgcn_s_setprio(1);
          for (int nt = 0; nt < 4; ++nt) {
            f32x4 z;
            for (int r = 0; r < 4; ++r) z[r] = 0.f;
            z = __builtin_amdgcn_mfma_f32_16x16x32_bf16(aq0, kc0[nt], z, 0, 0, 0);
            z = __builtin_amdgcn_mfma_f32_16x16x32_bf16(aq1, kc1[nt], z, 0, 0, 0);
            sc[nt] = z;
          }
          __builtin_amdgcn_s_setprio(0);

          float sv[4][4];
          for (int nt = 0; nt < 4; ++nt) {
            const int mcol = mods[kt * 64 + nt * 16 + l15];
            for (int r = 0; r < 4; ++r)
              sv[nt][r] = sc[nt][r] * KL2E + cm[mrow[r] * 3 + mcol];
          }
          if (kt * 64 + 63 > qw0) {    // tile intersects diagonal for this wave
            for (int nt = 0; nt < 4; ++nt) {
              const int col = kt * 64 + nt * 16 + l15;
              for (int r = 0; r < 4; ++r) {
                const int row = qw0 + quad * 4 + r;
                sv[nt][r] = (col <= row) ? sv[nt][r] : -1e30f;
              }
            }
          }
          short pb[4][4];
          for (int nt = 0; nt < 4; ++nt)
            for (int r = 0; r < 4; ++r) {
              const float pe = __builtin_exp2f(fminf(sv[nt][r], 86.56f));
              lsum[r] += pe;
              pb[nt][r] = f2bf(pe);
            }

          // P: C-layout -> A-layout via wave-local LDS strip (2-way banked)
          short* Pw = &Ps[w * 16 * 88];
          for (int nt = 0; nt < 4; ++nt)
            for (int r = 0; r < 4; ++r)
              Pw[(quad * 4 + r) * 88 + nt * 16 + l15] = pb[nt][r];
          asm volatile("s_waitcnt lgkmcnt(0)" ::: "memory");  // wave-local RAW drain

          __builtin_amdgcn_s_setprio(1);
          for (int kk = 0; kk < 2; ++kk) {
            const bf16x8 ap = *(const bf16x8*)&Pw[l15 * 88 + kk * 32 + quad * 8];
            for (int ni = 0; ni < 4; ++ni) {
              const bf16x8 bv = *(const bf16x8*)&Vt[cur][(ni * 16 + l15) * 88 + kk * 32 + quad * 8];
              acc_o[ni] = __builtin_amdgcn_mfma_f32_16x16x32_bf16(ap, bv, acc_o[ni], 0, 0, 0);
            }
          }
          __builtin_amdgcn_s_setprio(0);
        }
        cur ^= 1;
      }
    } else {
      __syncthreads();                 // keep barrier count uniform (unreachable
    }                                  // in practice: par<=3 <= ktmax>=1... safe)

    for (int off = 1; off < 16; off <<= 1)
      for (int r = 0; r < 4; ++r) lsum[r] += __shfl_xor(lsum[r], off);

    for (int ni = 0; ni < 4; ++ni) {
      const int col = h * 64 + ni * 16 + l15;
      for (int r = 0; r < 4; ++r) {
        const int row = qw0 + quad * 4 + r;
        POp[(long)row * HID + col] = f2bf(acc_o[ni][r]);
      }
    }
    if (l15 == 0) {
      for (int r = 0; r < 4; ++r) {
        const int row = qw0 + quad * 4 + r;
        PL[par * 32768 + row * 16 + h] = lsum[r];
      }
    }
  }
}

// Merge 4 parity partials -> CTX (bf16): O = (sum o_i)/(sum l_i).
__global__ __launch_bounds__(256) void attn_merge(
    const short* __restrict__ PO, const float* __restrict__ PL,
    short* __restrict__ CTX)
{
  const int row = blockIdx.x;
  const int t = threadIdx.x;
  const int h = t >> 4;
  const int d0 = (t & 15) * 4;
  float ls = 0.f;
#pragma unroll
  for (int i = 0; i < 4; ++i) ls += PL[i * 32768 + row * 16 + h];
  const float inv = 1.f / ls;
  const long b = (long)row * HID + h * 64 + d0;
  float o[4] = {0.f, 0.f, 0.f, 0.f};
#pragma unroll
  for (int i = 0; i < 4; ++i) {
    const bf16x4 v = *(const bf16x4*)&PO[i * POSTRIDE + b];
#pragma unroll
    for (int j = 0; j < 4; ++j) o[j] += bf2f(v[j]);
  }
  bf16x4 out;
#pragma unroll
  for (int j = 0; j < 4; ++j) out[j] = f2bf(o[j] * inv);
  *(bf16x4*)&CTX[b] = out;
}

extern "C" void kernel_launch(void* const* d_in, const int* in_sizes, int n_in,
                              void* d_out, int out_size, void* d_ws, size_t ws_size,
                              hipStream_t stream) {
  constexpr long M1 = 1024L * 1024L;
  int*   flags = (int*)d_ws;
  short* base  = (short*)d_ws + 128;
  // dead-after-QKV region (10MB): xb, Wqb, Wkb, Wvb
  short* xb  = base;            // 2M shorts
  short* Wqb = xb + 2 * M1;     // 1M
  short* Wkb = Wqb + M1;        // 1M
  short* Wvb = Wkb + M1;        // 1M
  // persistent: Wob, Qw, Kw, Vw, CTX
  short* Wob = Wvb + M1;        // 1M
  short* Qw  = Wob + M1;        // 2M
  short* Kw  = Qw + 2 * M1;     // 2M
  short* Vw  = Kw + 2 * M1;     // 2M
  short* CTX = Vw + 2 * M1;     // 2M  (ends at 14M shorts = 28MB)
  // attention partials (fresh region)
  short* PO4 = base + 14 * M1;  // 4 x 2M shorts = 16MB
  float* PL4 = (float*)(base + 22 * M1);  // 4 x 32768 floats = 512KB
  const int* modality = (const int*)d_in[11];

  convert5<<<dim3(512, 5), 256, 0, stream>>>(
      d_in[0], d_in[1], d_in[3], d_in[5], d_in[7],
      xb, Wqb, Wkb, Wvb, Wob, modality, flags);

  // QKV projection: 3 mats x 16 n-tiles x 16 m-tiles = 768 blocks, BK=64
  gemm_bt3<128, 64><<<dim3(48, 16), 256, 0, stream>>>(
      xb, Wqb, Wkb, Wvb, d_in[2], d_in[4], d_in[6],
      Qw, Kw, Vw, flags, 16, /*store_f32=*/0);
  // attention: (8 strip-pairs x 4 k-parities) x 16 heads = 512 blocks x 512 thr
  attn_split<<<dim3(32, NHEAD), 512, 0, stream>>>(
      Qw, Kw, Vw, modality, d_in[9], flags, PO4, PL4);
  attn_merge<<<dim3(S_LEN), 256, 0, stream>>>(PO4, PL4, CTX);
  // output projection: BM=BN=64 -> 16 n-tiles x 32 m-tiles = 512 blocks, BK=64
  gemm_bt3<64, 64><<<dim3(16, 32), 256, 0, stream>>>(
      CTX, Wob, Wob, Wob, d_in[8], d_in[8], d_in[8],
      d_out, d_out, d_out, flags, 16, /*store_f32=*/1);
}

// Round 11
// 175.960 us; speedup vs baseline: 1.2550x; 1.2550x over previous
//
#include <hip/hip_runtime.h>
#include <hip/hip_bf16.h>
#include <math.h>

#define S_LEN 2048
#define HID   1024
#define NHEAD 16

using bf16x8 = __attribute__((ext_vector_type(8))) short;
using bf16x4 = __attribute__((ext_vector_type(4))) short;
using f32x4  = __attribute__((ext_vector_type(4))) float;

__device__ __forceinline__ float bf2f(short s) {
  union { unsigned u; float f; } c;
  c.u = ((unsigned)(unsigned short)s) << 16;
  return c.f;
}
__device__ __forceinline__ short f2bf(float f) {
  union { float f; unsigned u; } c; c.f = f;
  unsigned u = c.u;
  unsigned r = (u + 0x7fffu + ((u >> 16) & 1u)) >> 16;
  return (short)r;
}
__device__ __forceinline__ float loadf(const void* base, long idx, int is_bf) {
  return is_bf ? bf2f(((const short*)base)[idx]) : ((const float*)base)[idx];
}
__device__ __forceinline__ void gl_lds16(const void* g, void* l) {
  __builtin_amdgcn_global_load_lds(
      (const __attribute__((address_space(1))) void*)g,
      (__attribute__((address_space(3))) void*)l, 16, 0, 0);
}

// Convert x + 4 weights to bf16 (or copy). blockIdx.y: 0=x (2M), 1..4=W (1M each).
// Detection folded in; block (0,0) publishes flags[0..1].
__global__ __launch_bounds__(256) void convert5(
    const void* __restrict__ s0, const void* __restrict__ s1, const void* __restrict__ s2,
    const void* __restrict__ s3, const void* __restrict__ s4,
    short* __restrict__ d0, short* __restrict__ d1, short* __restrict__ d2,
    short* __restrict__ d3, short* __restrict__ d4,
    const int* __restrict__ modw, int* __restrict__ flags) {
  __shared__ int sh_isbf;
  const int t = threadIdx.x;

  if (t < 64) {
    const unsigned* xw = (const unsigned*)s0;
    int cnt = 0;
    for (int i = t; i < 1024; i += 64) {
      const unsigned fld = (xw[i] >> 7) & 0xFFu;
      cnt += (fld >= 100u && fld <= 135u) ? 1 : 0;
    }
    for (int m = 1; m < 64; m <<= 1) cnt += __shfl_xor(cnt, m);
    if (t == 0) sh_isbf = (cnt >= 512) ? 1 : 0;
  }
  __syncthreads();
  const int is_bf = sh_isbf;

  if (blockIdx.x == 0 && blockIdx.y == 0 && t < 64) {
    int odd = 0;
    for (int i = 0; i < 4; ++i) {
      const int wv = modw[2 * (t + 64 * i) + 1];
      odd += (wv != 0) ? 1 : 0;
    }
    for (int m = 1; m < 64; m <<= 1) odd += __shfl_xor(odd, m);
    if (t == 0) {
      flags[0] = is_bf;
      flags[1] = (odd == 0) ? 1 : 0;
    }
  }

  const int a = blockIdx.y;
  const void* src = (a == 0) ? s0 : (a == 1) ? s1 : (a == 2) ? s2 : (a == 3) ? s3 : s4;
  short* dst = (a == 0) ? d0 : (a == 1) ? d1 : (a == 2) ? d2 : (a == 3) ? d3 : d4;
  const long n = (a == 0) ? (2L << 20) : (1L << 20);
  long i = (long)(blockIdx.x * 256 + t) * 8;
  const long stride = (long)gridDim.x * 256 * 8;
  if (is_bf) {
    for (; i < n; i += stride)
      *(bf16x8*)(dst + i) = *(const bf16x8*)((const short*)src + i);
  } else {
    for (; i < n; i += stride) {
      const float* p = (const float*)src + i;
      bf16x8 r;
#pragma unroll
      for (int j = 0; j < 8; ++j) r[j] = f2bf(p[j]);
      *(bf16x8*)(dst + i) = r;
    }
  }
}

// Pure-bf16 B^T GEMM, BM x BN tile, BK=64 staged as TWO 32-wide panels
// [buf][panel][row][32] so global_load_lds keeps linear 1KB regions and
// ds_read bank pattern stays identical to the verified BK=32 kernel.
// 2-phase double-buffered; ONE __syncthreads per 64-k step (half the barriers
// and vmcnt drains of the BK=32 version for the same bytes and MFMA count).
// C[m,n] = A[m,:].W[n,:] + bias[n]; fp32 acc.
// <128,64>: 4 waves 2m x 2n, MI=4 NI=2 (QKV). <64,64>: 1m x 4n, MI=4 NI=1.
template <int BM, int BN>
__global__ __launch_bounds__(256) void gemm_bt3(
    const short* __restrict__ A,
    const short* __restrict__ W0, const short* __restrict__ W1, const short* __restrict__ W2,
    const void* __restrict__ b0, const void* __restrict__ b1, const void* __restrict__ b2,
    void* __restrict__ C0, void* __restrict__ C1, void* __restrict__ C2,
    const int* __restrict__ flags, int nbn, int store_f32)
{
  constexpr int K = 1024;
  constexpr int N = 1024;
  constexpr int NKT = K / 64;               // 16 k-steps
  constexpr int WM = (BM == 128) ? 2 : 1;
  constexpr int WN = 4 / WM;
  constexpr int MI = (BM / 16) / WM;
  constexpr int NI = (BN / 16) / WN;
  constexpr int RPA = BM / 16;              // 1KB regions per A panel
  constexpr int RPB = BN / 16;
  __shared__ short As[2][2][BM * 32];
  __shared__ short Bs[2][2][BN * 32];

  const int t = threadIdx.x;
  const int w = t >> 6, lane = t & 63;
  const int l15 = lane & 15, quad = lane >> 4;
  const int wm = w / WN, wn = w % WN;
  const int is_bf = flags[0];

  const int mat = blockIdx.x / nbn;
  const int n0 = (blockIdx.x % nbn) * BN;
  const int m0 = blockIdx.y * BM;

  const short* W  = (mat == 0) ? W0 : (mat == 1 ? W1 : W2);
  const void* bia = (mat == 0) ? b0 : (mat == 1 ? b1 : b2);
  void*       C   = (mat == 0) ? C0 : (mat == 1 ? C1 : C2);

  f32x4 acc[MI][NI];
  for (int mi = 0; mi < MI; ++mi)
    for (int ni = 0; ni < NI; ++ni)
      for (int r = 0; r < 4; ++r) acc[mi][ni][r] = 0.f;

  // staging lane map: 16 rows x 64B per 1KB region
  const int srow = lane >> 2;               // 0..15
  const int sch  = (lane & 3) * 8;          // 0,8,16,24 shorts

  auto stage = [&](int kt, int buf) {
    for (int g = w; g < 2 * RPA; g += 4) {  // A regions: panel p, rows r0..r0+15
      const int p = g / RPA, r0 = (g % RPA) * 16;
      gl_lds16(A + (long)(m0 + r0 + srow) * K + kt * 64 + p * 32 + sch,
               &As[buf][p][r0 * 32]);
    }
    for (int g = w; g < 2 * RPB; g += 4) {
      const int p = g / RPB, r0 = (g % RPB) * 16;
      gl_lds16(W + (long)(n0 + r0 + srow) * K + kt * 64 + p * 32 + sch,
               &Bs[buf][p][r0 * 32]);
    }
  };

  stage(0, 0);
  int cur = 0;
  for (int kt = 0; kt < NKT; ++kt) {
    __syncthreads();                        // step kt landed; prev reads done
    if (kt + 1 < NKT) stage(kt + 1, cur ^ 1);  // next step flies under MFMA

    bf16x8 af[MI][2], bfr[NI][2];
    for (int p = 0; p < 2; ++p) {
      for (int mi = 0; mi < MI; ++mi)
        af[mi][p] = *(const bf16x8*)&As[cur][p][(wm * (MI * 16) + mi * 16 + l15) * 32 + quad * 8];
      for (int ni = 0; ni < NI; ++ni)
        bfr[ni][p] = *(const bf16x8*)&Bs[cur][p][(wn * (NI * 16) + ni * 16 + l15) * 32 + quad * 8];
    }
    for (int p = 0; p < 2; ++p)
      for (int mi = 0; mi < MI; ++mi)
        for (int ni = 0; ni < NI; ++ni)
          acc[mi][ni] = __builtin_amdgcn_mfma_f32_16x16x32_bf16(af[mi][p], bfr[ni][p], acc[mi][ni], 0, 0, 0);
    cur ^= 1;
  }

  for (int ni = 0; ni < NI; ++ni) {
    const int col = n0 + wn * (NI * 16) + ni * 16 + l15;
    const float bv = loadf(bia, col, is_bf);
    for (int mi = 0; mi < MI; ++mi) {
      const int row = m0 + wm * (MI * 16) + mi * 16 + quad * 4;
      for (int r = 0; r < 4; ++r) {
        const float v = acc[mi][ni][r] + bv;
        const long idx = (long)(row + r) * N + col;
        if (store_f32) ((float*)C)[idx] = v;
        else           ((short*)C)[idx] = f2bf(v);
      }
    }
  }
}

// ============================================================================
// Flash attention (R8/R9 structure, session best): 8-wave blocks, each staged
// 64-k K/V tile serves 128 q-rows; per wave 16 q-rows with the R2 tile body.
// 4-way split-K; strip pairs (p,15-p). MAX-FREE softmax.
// ============================================================================
#define POSTRIDE (2L * 1024 * 1024)
__global__ __launch_bounds__(512) void attn_split(
    const short* __restrict__ Q, const short* __restrict__ Kg, const short* __restrict__ Vg,
    const int* __restrict__ mod, const void* __restrict__ cmw,
    const int* __restrict__ flags,
    short* __restrict__ PO, float* __restrict__ PL)
{
  __shared__ short Ks[64 * 80];
  __shared__ short Vt[64 * 80];
  __shared__ short Ps[8 * 16 * 80];
  __shared__ float cm[9];
  __shared__ int mods[2048];

  const int t = threadIdx.x;            // 0..511
  const int w = t >> 6, lane = t & 63;  // 8 waves
  const int l15 = lane & 15, quad = lane >> 4;
  const int h = blockIdx.y;
  const int p   = blockIdx.x >> 2;      // 0..7 -> strips {p, 15-p}
  const int par = blockIdx.x & 3;       // k-parity 0..3
  const int m64 = flags[1];
  const float KL2E = 0.125f * 1.44269504089f;   // 0.125 * log2(e)

  if (t < 9) cm[t] = loadf(cmw, t, flags[0]) * 1.44269504089f;
  for (int i = t; i < 2048; i += 512) mods[i] = mod[i << m64];
  __syncthreads();

  short* POp = PO + (long)par * POSTRIDE;
  const int krow = t >> 3, kch = (t & 7) * 8;   // K: 64 rows x 8 chunks
  const int vkp = t & 63, vdc = (t >> 6) * 8;   // V: 64 k x 8 d-groups

  for (int si = 0; si < 2; ++si) {
    const int strip = si ? 15 - p : p;
    const int q0 = strip * 128;
    const int ktmax = 2 * strip + 1;
    const int qw0 = q0 + w * 16;        // this wave's first q-row

    const short* qb = Q + (long)(qw0 + l15) * HID + h * 64 + quad * 8;
    const bf16x8 aq0 = *(const bf16x8*)qb;
    const bf16x8 aq1 = *(const bf16x8*)(qb + 32);

    int mrow[4];
    for (int r = 0; r < 4; ++r) mrow[r] = mods[qw0 + quad * 4 + r];

    float lsum[4];
    f32x4 acc_o[4];
    for (int r = 0; r < 4; ++r) lsum[r] = 0.f;
    for (int ni = 0; ni < 4; ++ni)
      for (int r = 0; r < 4; ++r) acc_o[ni][r] = 0.f;

    bf16x8 rk, rv;
    auto preload = [&](int kt) {
      const long kb = (long)(kt * 64) * HID + h * 64;
      rk = *(const bf16x8*)(Kg + kb + (long)krow * HID + kch);
      rv = *(const bf16x8*)(Vg + kb + (long)vkp * HID + vdc);
    };

    if (par <= ktmax) {
      preload(par);
      for (int kt = par; kt <= ktmax; kt += 4) {
        __syncthreads();               // prior readers of Ks/Vt done
        *(bf16x8*)&Ks[krow * 80 + kch] = rk;
#pragma unroll
        for (int j = 0; j < 8; ++j) Vt[(vdc + j) * 80 + vkp] = rv[j];
        __syncthreads();               // tile visible
        if (kt + 4 <= ktmax) preload(kt + 4);

        if (kt * 64 <= qw0 + 15) {     // not fully above diagonal for this wave
          f32x4 sc[4];
          __builtin_amdgcn_s_setprio(1);
          for (int nt = 0; nt < 4; ++nt) {
            const bf16x8 kb0 = *(const bf16x8*)&Ks[(nt * 16 + l15) * 80 + quad * 8];
            const bf16x8 kb1 = *(const bf16x8*)&Ks[(nt * 16 + l15) * 80 + 32 + quad * 8];
            f32x4 z;
            for (int r = 0; r < 4; ++r) z[r] = 0.f;
            z = __builtin_amdgcn_mfma_f32_16x16x32_bf16(aq0, kb0, z, 0, 0, 0);
            z = __builtin_amdgcn_mfma_f32_16x16x32_bf16(aq1, kb1, z, 0, 0, 0);
            sc[nt] = z;
          }
          __builtin_amdgcn_s_setprio(0);

          float sv[4][4];
          for (int nt = 0; nt < 4; ++nt) {
            const int mcol = mods[kt * 64 + nt * 16 + l15];
            for (int r = 0; r < 4; ++r)
              sv[nt][r] = sc[nt][r] * KL2E + cm[mrow[r] * 3 + mcol];
          }
          if (kt * 64 + 63 > qw0) {    // tile intersects diagonal for this wave
            for (int nt = 0; nt < 4; ++nt) {
              const int col = kt * 64 + nt * 16 + l15;
              for (int r = 0; r < 4; ++r) {
                const int row = qw0 + quad * 4 + r;
                sv[nt][r] = (col <= row) ? sv[nt][r] : -1e30f;
              }
            }
          }
          short pb[4][4];
          for (int nt = 0; nt < 4; ++nt)
            for (int r = 0; r < 4; ++r) {
              const float pe = __builtin_exp2f(fminf(sv[nt][r], 86.56f));
              lsum[r] += pe;
              pb[nt][r] = f2bf(pe);
            }

          short* Pw = &Ps[w * 16 * 80];
          for (int nt = 0; nt < 4; ++nt)
            for (int r = 0; r < 4; ++r)
              Pw[(quad * 4 + r) * 80 + nt * 16 + l15] = pb[nt][r];
          asm volatile("s_waitcnt lgkmcnt(0)" ::: "memory");  // wave-local RAW drain

          __builtin_amdgcn_s_setprio(1);
          for (int kk = 0; kk < 2; ++kk) {
            const bf16x8 ap = *(const bf16x8*)&Pw[l15 * 80 + kk * 32 + quad * 8];
            for (int ni = 0; ni < 4; ++ni) {
              const bf16x8 bv = *(const bf16x8*)&Vt[(ni * 16 + l15) * 80 + kk * 32 + quad * 8];
              acc_o[ni] = __builtin_amdgcn_mfma_f32_16x16x32_bf16(ap, bv, acc_o[ni], 0, 0, 0);
            }
          }
          __builtin_amdgcn_s_setprio(0);
        }
      }
    }

    for (int off = 1; off < 16; off <<= 1)
      for (int r = 0; r < 4; ++r) lsum[r] += __shfl_xor(lsum[r], off);

    for (int ni = 0; ni < 4; ++ni) {
      const int col = h * 64 + ni * 16 + l15;
      for (int r = 0; r < 4; ++r) {
        const int row = qw0 + quad * 4 + r;
        POp[(long)row * HID + col] = f2bf(acc_o[ni][r]);
      }
    }
    if (l15 == 0) {
      for (int r = 0; r < 4; ++r) {
        const int row = qw0 + quad * 4 + r;
        PL[par * 32768 + row * 16 + h] = lsum[r];
      }
    }
  }
}

// Merge 4 parity partials -> CTX (bf16): O = (sum o_i)/(sum l_i).
__global__ __launch_bounds__(256) void attn_merge(
    const short* __restrict__ PO, const float* __restrict__ PL,
    short* __restrict__ CTX)
{
  const int row = blockIdx.x;
  const int t = threadIdx.x;
  const int h = t >> 4;
  const int d0 = (t & 15) * 4;
  float ls = 0.f;
#pragma unroll
  for (int i = 0; i < 4; ++i) ls += PL[i * 32768 + row * 16 + h];
  const float inv = 1.f / ls;
  const long b = (long)row * HID + h * 64 + d0;
  float o[4] = {0.f, 0.f, 0.f, 0.f};
#pragma unroll
  for (int i = 0; i < 4; ++i) {
    const bf16x4 v = *(const bf16x4*)&PO[i * POSTRIDE + b];
#pragma unroll
    for (int j = 0; j < 4; ++j) o[j] += bf2f(v[j]);
  }
  bf16x4 out;
#pragma unroll
  for (int j = 0; j < 4; ++j) out[j] = f2bf(o[j] * inv);
  *(bf16x4*)&CTX[b] = out;
}

extern "C" void kernel_launch(void* const* d_in, const int* in_sizes, int n_in,
                              void* d_out, int out_size, void* d_ws, size_t ws_size,
                              hipStream_t stream) {
  constexpr long M1 = 1024L * 1024L;
  int*   flags = (int*)d_ws;
  short* base  = (short*)d_ws + 128;
  // dead-after-QKV region (10MB): xb, Wqb, Wkb, Wvb
  short* xb  = base;            // 2M shorts
  short* Wqb = xb + 2 * M1;     // 1M
  short* Wkb = Wqb + M1;        // 1M
  short* Wvb = Wkb + M1;        // 1M
  // persistent: Wob, Qw, Kw, Vw, CTX
  short* Wob = Wvb + M1;        // 1M
  short* Qw  = Wob + M1;        // 2M
  short* Kw  = Qw + 2 * M1;     // 2M
  short* Vw  = Kw + 2 * M1;     // 2M
  short* CTX = Vw + 2 * M1;     // 2M  (ends at 14M shorts = 28MB)
  // attention partials (fresh region)
  short* PO4 = base + 14 * M1;  // 4 x 2M shorts = 16MB
  float* PL4 = (float*)(base + 22 * M1);  // 4 x 32768 floats = 512KB
  const int* modality = (const int*)d_in[11];

  convert5<<<dim3(512, 5), 256, 0, stream>>>(
      d_in[0], d_in[1], d_in[3], d_in[5], d_in[7],
      xb, Wqb, Wkb, Wvb, Wob, modality, flags);

  // QKV projection: 3 mats x 16 n-tiles x 16 m-tiles = 768 blocks, BK=64
  gemm_bt3<128, 64><<<dim3(48, 16), 256, 0, stream>>>(
      xb, Wqb, Wkb, Wvb, d_in[2], d_in[4], d_in[6],
      Qw, Kw, Vw, flags, 16, /*store_f32=*/0);
  // attention: (8 strip-pairs x 4 k-parities) x 16 heads = 512 blocks x 512 thr
  attn_split<<<dim3(32, NHEAD), 512, 0, stream>>>(
      Qw, Kw, Vw, modality, d_in[9], flags, PO4, PL4);
  attn_merge<<<dim3(S_LEN), 256, 0, stream>>>(PO4, PL4, CTX);
  // output projection: BM=BN=64 -> 16 n-tiles x 32 m-tiles = 512 blocks, BK=64
  gemm_bt3<64, 64><<<dim3(16, 32), 256, 0, stream>>>(
      CTX, Wob, Wob, Wob, d_in[8], d_in[8], d_in[8],
      d_out, d_out, d_out, flags, 16, /*store_f32=*/1);
}